// Round 2
// baseline (9456.555 us; speedup 1.0000x reference)
//
#include <hip/hip_runtime.h>

#define NUM_USERS 100000
#define NUM_ITEMS 150000
#define N_NODES   250000
#define DIM       64
#define N_EDGES   2000000
#define EPS       0.2

// ---------------------------------------------------------------------------
// init: A(double) = concat(user_emb, item_emb); acc(fp32, in d_out) = same
// ---------------------------------------------------------------------------
__global__ void init_kernel(const float* __restrict__ user,
                            const float* __restrict__ item,
                            double* __restrict__ A,
                            float* __restrict__ acc) {
    int i = blockIdx.x * blockDim.x + threadIdx.x;
    const int userN = NUM_USERS * DIM;
    const int total = N_NODES * DIM;
    if (i >= total) return;
    float v = (i < userN) ? user[i] : item[i - userN];
    A[i]   = (double)v;
    acc[i] = v;
}

// ---------------------------------------------------------------------------
// scatter: B[dst[e]] += vals[e] * A[src[e]]  (fp64, HW fp64 atomics)
// 16 threads per edge, 4 dims each
// ---------------------------------------------------------------------------
__global__ void scatter_kernel(const double* __restrict__ A,
                               double* __restrict__ B,
                               const int* __restrict__ src,
                               const int* __restrict__ dst,
                               const float* __restrict__ vals) {
    long long t = (long long)blockIdx.x * blockDim.x + threadIdx.x;
    int e = (int)(t >> 4);
    int c = (int)(t & 15);
    if (e >= N_EDGES) return;
    int s = src[e];
    int d = dst[e];
    double v = (double)vals[e];
    const double* ap = A + (long long)s * DIM + c * 4;
    double2 m0 = *reinterpret_cast<const double2*>(ap);
    double2 m1 = *reinterpret_cast<const double2*>(ap + 2);
    double* bp = B + (long long)d * DIM + c * 4;
    unsafeAtomicAdd(bp + 0, v * m0.x);
    unsafeAtomicAdd(bp + 1, v * m0.y);
    unsafeAtomicAdd(bp + 2, v * m1.x);
    unsafeAtomicAdd(bp + 3, v * m1.y);
}

// ---------------------------------------------------------------------------
// perturb: one 64-lane wave per node (lane == dim), all math fp64
//   ne  = seg + sign(seg) * l2norm(noise_row) * EPS
//   acc(fp32) += ne ; A(double) = ne
//   WRITE_CL (k==0): cl_out = l2norm(ne)        (fp32)
//   FINALIZE (k==2): acc = l2norm(acc + ne)     (fp32)
// ---------------------------------------------------------------------------
template<bool WRITE_CL, bool FINALIZE>
__global__ void perturb_kernel(const double* __restrict__ B,
                               const float* __restrict__ noise,
                               double* __restrict__ A,
                               float* __restrict__ acc,
                               float* __restrict__ cl_out) {
    int node = blockIdx.x * (blockDim.x >> 6) + (threadIdx.x >> 6);
    int lane = threadIdx.x & 63;
    if (node >= N_NODES) return;
    long long base = (long long)node * DIM + lane;

    double nz = (double)noise[base];
    double ss = nz * nz;
    #pragma unroll
    for (int off = 32; off; off >>= 1) ss += __shfl_xor(ss, off);
    double nrm = nz * (1.0 / sqrt(fmax(ss, 1e-24)));

    double seg = B[base];
    double sg = (seg > 0.0) ? 1.0 : ((seg < 0.0) ? -1.0 : 0.0);
    double ne = seg + sg * nrm * EPS;

    if (!FINALIZE) A[base] = ne;

    double a = (double)acc[base] + ne;

    if (WRITE_CL) {
        double s2 = ne * ne;
        #pragma unroll
        for (int off = 32; off; off >>= 1) s2 += __shfl_xor(s2, off);
        cl_out[base] = (float)(ne * (1.0 / sqrt(fmax(s2, 1e-24))));
    }

    if (FINALIZE) {
        double s3 = a * a;
        #pragma unroll
        for (int off = 32; off; off >>= 1) s3 += __shfl_xor(s3, off);
        acc[base] = (float)(a * (1.0 / sqrt(fmax(s3, 1e-24))));
    } else {
        acc[base] = (float)a;
    }
}

extern "C" void kernel_launch(void* const* d_in, const int* in_sizes, int n_in,
                              void* d_out, int out_size, void* d_ws, size_t ws_size,
                              hipStream_t stream) {
    const float* user  = (const float*)d_in[0];
    const float* item  = (const float*)d_in[1];
    const float* vals  = (const float*)d_in[2];
    const float* noise = (const float*)d_in[3];
    const int*   src   = (const int*)d_in[4];
    const int*   dst   = (const int*)d_in[5];

    float* out = (float*)d_out;
    float* acc = out;                                  // 16M fp32 (users+items)
    float* cl  = out + (long long)N_NODES * DIM;       // 16M fp32 (cl region)

    double* A = (double*)d_ws;                         // 128 MB fp64 emb
    double* B = A + (long long)N_NODES * DIM;          // 128 MB fp64 segment sums

    const int totalF = N_NODES * DIM;                  // 16M
    init_kernel<<<(totalF + 255) / 256, 256, 0, stream>>>(user, item, A, acc);

    const long long scatterThreads = (long long)N_EDGES * 16;
    const int scatterBlocks = (int)((scatterThreads + 255) / 256);  // 125000
    const int perturbBlocks = (N_NODES + 3) / 4;                    // 62500 (4 waves/block)

    for (int k = 0; k < 3; ++k) {
        hipMemsetAsync(B, 0, (size_t)N_NODES * DIM * sizeof(double), stream);
        scatter_kernel<<<scatterBlocks, 256, 0, stream>>>(A, B, src, dst, vals);
        const float* nk = noise + (long long)k * N_NODES * DIM;
        if (k == 0)
            perturb_kernel<true,  false><<<perturbBlocks, 256, 0, stream>>>(B, nk, A, acc, cl);
        else if (k == 1)
            perturb_kernel<false, false><<<perturbBlocks, 256, 0, stream>>>(B, nk, A, acc, cl);
        else
            perturb_kernel<false, true ><<<perturbBlocks, 256, 0, stream>>>(B, nk, A, acc, cl);
    }
}

// Round 3
// 1282.400 us; speedup vs baseline: 7.3741x; 7.3741x over previous
//
#include <hip/hip_runtime.h>

#define NUM_USERS 100000
#define NUM_ITEMS 150000
#define N_NODES   250000
#define DIM       64
#define N_EDGES   2000000
#define EPS       0.2

#define SCAN_BS 1024
#define SCAN_NB ((N_NODES + SCAN_BS - 1) / SCAN_BS)   // 245

// ---------------------------------------------------------------------------
// init: A0(double) = concat(user_emb, item_emb); acc(fp32, in d_out) = same
// ---------------------------------------------------------------------------
__global__ void init_kernel(const float* __restrict__ user,
                            const float* __restrict__ item,
                            double* __restrict__ A,
                            float* __restrict__ acc) {
    int i = blockIdx.x * blockDim.x + threadIdx.x;
    const int userN = NUM_USERS * DIM;
    const int total = N_NODES * DIM;
    if (i >= total) return;
    float v = (i < userN) ? user[i] : item[i - userN];
    A[i]   = (double)v;
    acc[i] = v;
}

// ---------------------------------------------------------------------------
// CSR build: histogram of dst
// ---------------------------------------------------------------------------
__global__ void hist_kernel(const int* __restrict__ dst, int* __restrict__ counts) {
    int e = blockIdx.x * blockDim.x + threadIdx.x;
    if (e >= N_EDGES) return;
    atomicAdd(&counts[dst[e]], 1);
}

// in-place inclusive scan per 1024-block; block totals -> bsums
__global__ void scan_block(int* __restrict__ data, int* __restrict__ bsums) {
    __shared__ int tmp[SCAN_BS];
    int gid = blockIdx.x * SCAN_BS + threadIdx.x;
    int v = (gid < N_NODES) ? data[gid] : 0;
    tmp[threadIdx.x] = v;
    __syncthreads();
    for (int off = 1; off < SCAN_BS; off <<= 1) {
        int t = (threadIdx.x >= off) ? tmp[threadIdx.x - off] : 0;
        __syncthreads();
        tmp[threadIdx.x] += t;
        __syncthreads();
    }
    if (gid < N_NODES) data[gid] = tmp[threadIdx.x];
    if (threadIdx.x == SCAN_BS - 1) bsums[blockIdx.x] = tmp[SCAN_BS - 1];
}

// exclusive scan of the 245 block sums (tiny; one thread)
__global__ void scan_bsums(int* __restrict__ bsums) {
    if (threadIdx.x == 0 && blockIdx.x == 0) {
        int run = 0;
        for (int i = 0; i < SCAN_NB; ++i) { int t = bsums[i]; bsums[i] = run; run += t; }
    }
}

// row_ptr[i+1] = incl[i] + bsums[block(i)]; row_ptr[0] = 0
__global__ void scan_finalize(const int* __restrict__ incl, const int* __restrict__ bsums,
                              int* __restrict__ row_ptr) {
    int gid = blockIdx.x * SCAN_BS + threadIdx.x;
    if (gid < N_NODES) row_ptr[gid + 1] = incl[gid] + bsums[gid >> 10];
    if (gid == 0) row_ptr[0] = 0;
}

// scatter edges into CSR slots
__global__ void fill_kernel(const int* __restrict__ src, const int* __restrict__ dst,
                            const float* __restrict__ vals,
                            const int* __restrict__ row_ptr, int* __restrict__ fill,
                            int* __restrict__ e_src, float* __restrict__ e_val) {
    int e = blockIdx.x * blockDim.x + threadIdx.x;
    if (e >= N_EDGES) return;
    int d = dst[e];
    int pos = row_ptr[d] + atomicAdd(&fill[d], 1);
    e_src[pos] = src[e];
    e_val[pos] = vals[e];
}

// ---------------------------------------------------------------------------
// fused layer: one 64-lane wave per node (lane == dim)
//   seg = sum over in-edges of val * Ain[src][lane]     (fp64 gather-sum)
//   ne  = seg + sign(seg) * l2norm(noise_row) * EPS
//   acc(fp32) += ne ; Aout(double) = ne
//   WRITE_CL (k==0): cl_out = l2norm(ne)
//   FINALIZE (k==2): acc = l2norm(acc + ne)
// ---------------------------------------------------------------------------
template<bool WRITE_CL, bool FINALIZE>
__global__ void layer_kernel(const double* __restrict__ Ain,
                             double* __restrict__ Aout,
                             const int* __restrict__ row_ptr,
                             const int* __restrict__ e_src,
                             const float* __restrict__ e_val,
                             const float* __restrict__ noise,
                             float* __restrict__ acc,
                             float* __restrict__ cl_out) {
    int node = blockIdx.x * (blockDim.x >> 6) + (threadIdx.x >> 6);
    int lane = threadIdx.x & 63;
    if (node >= N_NODES) return;
    long long base = (long long)node * DIM + lane;

    int beg = row_ptr[node];
    int end = row_ptr[node + 1];

    double seg0 = 0.0, seg1 = 0.0;
    int j = beg;
    for (; j + 1 < end; j += 2) {
        int    s0 = e_src[j],     s1 = e_src[j + 1];
        double v0 = (double)e_val[j], v1 = (double)e_val[j + 1];
        seg0 += v0 * Ain[(long long)s0 * DIM + lane];
        seg1 += v1 * Ain[(long long)s1 * DIM + lane];
    }
    if (j < end) {
        seg0 += (double)e_val[j] * Ain[(long long)e_src[j] * DIM + lane];
    }
    double seg = seg0 + seg1;

    float nzf = noise[base];
    double nz = (double)nzf;
    double ss = nz * nz;
    #pragma unroll
    for (int off = 32; off; off >>= 1) ss += __shfl_xor(ss, off);
    double nrm = nz * (1.0 / sqrt(fmax(ss, 1e-24)));

    double sg = (seg > 0.0) ? 1.0 : ((seg < 0.0) ? -1.0 : 0.0);
    double ne = seg + sg * nrm * EPS;

    if (!FINALIZE) Aout[base] = ne;

    double a = (double)acc[base] + ne;

    if (WRITE_CL) {
        double s2 = ne * ne;
        #pragma unroll
        for (int off = 32; off; off >>= 1) s2 += __shfl_xor(s2, off);
        cl_out[base] = (float)(ne * (1.0 / sqrt(fmax(s2, 1e-24))));
    }

    if (FINALIZE) {
        double s3 = a * a;
        #pragma unroll
        for (int off = 32; off; off >>= 1) s3 += __shfl_xor(s3, off);
        acc[base] = (float)(a * (1.0 / sqrt(fmax(s3, 1e-24))));
    } else {
        acc[base] = (float)a;
    }
}

extern "C" void kernel_launch(void* const* d_in, const int* in_sizes, int n_in,
                              void* d_out, int out_size, void* d_ws, size_t ws_size,
                              hipStream_t stream) {
    const float* user  = (const float*)d_in[0];
    const float* item  = (const float*)d_in[1];
    const float* vals  = (const float*)d_in[2];
    const float* noise = (const float*)d_in[3];
    const int*   src   = (const int*)d_in[4];
    const int*   dst   = (const int*)d_in[5];

    float* out = (float*)d_out;
    float* acc = out;                                  // 16M fp32 (users+items)
    float* cl  = out + (long long)N_NODES * DIM;       // 16M fp32 (cl region)

    char* p = (char*)d_ws;
    double* A0 = (double*)p;  p += (size_t)N_NODES * DIM * sizeof(double);   // 128 MB
    double* A1 = (double*)p;  p += (size_t)N_NODES * DIM * sizeof(double);   // 128 MB
    int* row_ptr = (int*)p;   p += ((size_t)(N_NODES + 1) * 4 + 255) & ~255ull;
    int* fill    = (int*)p;   p += ((size_t)N_NODES * 4 + 255) & ~255ull;
    int* bsums   = (int*)p;   p += 4096;
    int* e_src   = (int*)p;   p += (size_t)N_EDGES * 4;                      // 8 MB
    float* e_val = (float*)p;                                               // 8 MB

    const int edgeBlocks = (N_EDGES + 255) / 256;      // 7813
    const int totalF = N_NODES * DIM;                  // 16M

    // --- CSR build ---
    hipMemsetAsync(fill, 0, (size_t)N_NODES * 4, stream);
    hist_kernel<<<edgeBlocks, 256, 0, stream>>>(dst, fill);
    scan_block<<<SCAN_NB, SCAN_BS, 0, stream>>>(fill, bsums);
    scan_bsums<<<1, 64, 0, stream>>>(bsums);
    scan_finalize<<<SCAN_NB, SCAN_BS, 0, stream>>>(fill, bsums, row_ptr);
    hipMemsetAsync(fill, 0, (size_t)N_NODES * 4, stream);
    fill_kernel<<<edgeBlocks, 256, 0, stream>>>(src, dst, vals, row_ptr, fill, e_src, e_val);

    // --- init embeddings ---
    init_kernel<<<(totalF + 255) / 256, 256, 0, stream>>>(user, item, A0, acc);

    // --- 3 fused layers (ping-pong A0/A1) ---
    const int layerBlocks = (N_NODES + 3) / 4;         // 62500 (4 waves/block)
    const float* n0 = noise;
    const float* n1 = noise + (long long)N_NODES * DIM;
    const float* n2 = noise + 2LL * N_NODES * DIM;
    layer_kernel<true,  false><<<layerBlocks, 256, 0, stream>>>(A0, A1, row_ptr, e_src, e_val, n0, acc, cl);
    layer_kernel<false, false><<<layerBlocks, 256, 0, stream>>>(A1, A0, row_ptr, e_src, e_val, n1, acc, cl);
    layer_kernel<false, true ><<<layerBlocks, 256, 0, stream>>>(A0, A1, row_ptr, e_src, e_val, n2, acc, cl);
}